// Round 15
// baseline (999.048 us; speedup 1.0000x reference)
//
#include <hip/hip_runtime.h>
#include <hip/hip_bf16.h>
#include <math.h>

#define NTOK 8192     // B*T
#define DD   1024
#define HH   4096
#define NE   8
#define BM 128
#define BN 128
#define BK 64
#define SLOT_CAP (2 * NTOK + NE * BM)   // 17408
#define GATE_BLOCKS 512
#define CVT_BLOCKS  2048

typedef __bf16 bf16;
typedef __bf16 bf16x8 __attribute__((ext_vector_type(8)));
typedef __bf16 bf16x4 __attribute__((ext_vector_type(4)));
typedef float  f32x4  __attribute__((ext_vector_type(4)));

typedef __attribute__((address_space(3))) unsigned char lds_u8;
typedef const __attribute__((address_space(1))) unsigned char g_u8;

__device__ __forceinline__ void gload16(const bf16* g, bf16* l) {
  __builtin_amdgcn_global_load_lds((g_u8*)g, (lds_u8*)l, 16, 0, 0);
}

__device__ __forceinline__ float softplus_f(float v) {
  return fmaxf(v, 0.f) + log1pf(expf(-fabsf(v)));
}

// ---------------- K1: FUSED gate + weight-convert ----------------
// Blocks [0, GATE_BLOCKS): noisy-top2 gating, 4 waves/block, 4 tokens per wave
// (VALU/L1-bound). Blocks [GATE_BLOCKS, GATE_BLOCKS+CVT_BLOCKS): w1/w2 f32->bf16
// grid-stride convert (pure-BW). Fusing lets the two phases run CONCURRENTLY
// on complementary resources instead of serializing on the stream (~-60 us).
__global__ __launch_bounds__(256) void moe_gate_cvt_kernel(
    const float* __restrict__ x, const float* __restrict__ noise,
    const float* __restrict__ gate_w, const float* __restrict__ gate_b,
    const float* __restrict__ var_w,  const float* __restrict__ var_b,
    float* __restrict__ coef2, int* __restrict__ t2e, int* __restrict__ counts,
    bf16* __restrict__ xb,
    const float* __restrict__ w1, bf16* __restrict__ w1b, int n41,
    const float* __restrict__ w2, bf16* __restrict__ w2b, int n42)
{
  if (blockIdx.x >= GATE_BLOCKS) {
    // ---- weight conversion arm ----
    const int i0 = (blockIdx.x - GATE_BLOCKS) * 256 + threadIdx.x;
    const int stride = CVT_BLOCKS * 256;
    for (int i = i0; i < n41 + n42; i += stride) {
      const float* s = (i < n41) ? w1 : w2;
      bf16* d = (i < n41) ? w1b : w2b;
      const int j = (i < n41) ? i : i - n41;
      const float4 f = ((const float4*)s)[j];
      bf16x4 v;
      v[0] = (bf16)f.x; v[1] = (bf16)f.y; v[2] = (bf16)f.z; v[3] = (bf16)f.w;
      ((bf16x4*)d)[j] = v;
    }
    return;
  }
  // ---- gating arm: wave w handles tokens blockIdx*16 + w*4 .. +3 ----
  const int lane = threadIdx.x & 63;
  const int wave = threadIdx.x >> 6;
  const float4* gw4 = (const float4*)gate_w;
  const float4* vw4 = (const float4*)var_w;
  for (int tt = 0; tt < 4; ++tt) {
    const int t = blockIdx.x * 16 + wave * 4 + tt;
    const float4* x4 = (const float4*)(x + (size_t)t * DD);
    bf16x4* xb4 = (bf16x4*)(xb + (size_t)t * DD);
    float pg[NE], pv[NE];
    #pragma unroll
    for (int e = 0; e < NE; ++e) { pg[e] = 0.f; pv[e] = 0.f; }
    #pragma unroll
    for (int i = 0; i < DD / 256; ++i) {
      const int d4 = i * 64 + lane;
      const float4 f = x4[d4];
      bf16x4 v;
      v[0] = (bf16)f.x; v[1] = (bf16)f.y; v[2] = (bf16)f.z; v[3] = (bf16)f.w;
      xb4[d4] = v;
      #pragma unroll
      for (int e = 0; e < NE; ++e) {
        const float4 g = gw4[e * 256 + d4];
        pg[e] = fmaf(f.x, g.x, fmaf(f.y, g.y, fmaf(f.z, g.z, fmaf(f.w, g.w, pg[e]))));
        const float4 w = vw4[e * 256 + d4];
        pv[e] = fmaf(f.x, w.x, fmaf(f.y, w.y, fmaf(f.z, w.z, fmaf(f.w, w.w, pv[e]))));
      }
    }
    #pragma unroll
    for (int e = 0; e < NE; ++e) {
      #pragma unroll
      for (int off = 32; off; off >>= 1) {
        pg[e] += __shfl_xor(pg[e], off);
        pv[e] += __shfl_xor(pv[e], off);
      }
    }
    if (lane == 0) {
      float noisy[NE];
      #pragma unroll
      for (int e = 0; e < NE; ++e) {
        const float lg = pg[e] + gate_b[e];
        const float sd = softplus_f(pv[e] + var_b[e]);
        noisy[e] = lg + noise[t * NE + e] * sd;
      }
      int i1 = 0; float n1 = noisy[0];
      #pragma unroll
      for (int e = 1; e < NE; ++e) if (noisy[e] > n1) { n1 = noisy[e]; i1 = e; }
      int i2 = -1; float n2 = -3.0e38f;
      #pragma unroll
      for (int e = 0; e < NE; ++e) if (e != i1 && noisy[e] > n2) { n2 = noisy[e]; i2 = e; }
      const float e2 = expf(n2 - n1);
      const float den = 1.f + e2;
      coef2[t * 2 + 0] = 1.f / den;
      coef2[t * 2 + 1] = e2 / den;
      t2e[t * 2 + 0] = i1;
      t2e[t * 2 + 1] = i2;
      atomicAdd(&counts[i1], 1);
      atomicAdd(&counts[i2], 1);
    }
  }
}

// ---------------- K2: padded segment offsets (pad to BM=128) ----------------
__global__ void moe_offsets_kernel(const int* __restrict__ counts, int* __restrict__ po) {
  if (threadIdx.x == 0) {
    int acc = 0;
    po[0] = 0;
    for (int e = 0; e < NE; ++e) {
      acc += ((counts[e] + BM - 1) / BM) * BM;
      po[e + 1] = acc;
    }
  }
}

// ---------------- K3: scatter tokens into padded slots ----------------
__global__ __launch_bounds__(256) void moe_scatter_kernel(
    const int* __restrict__ t2e, const float* __restrict__ coef2,
    const int* __restrict__ po, int* __restrict__ cnt2,
    int* __restrict__ assign_tok, float* __restrict__ slot_coef)
{
  const int t = blockIdx.x * 256 + threadIdx.x;
  if (t >= NTOK) return;
  #pragma unroll
  for (int k = 0; k < 2; ++k) {
    const int e = t2e[t * 2 + k];
    const int pos = atomicAdd(&cnt2[e], 1);
    const int slot = po[e] + pos;
    assign_tok[slot] = t;
    slot_coef[slot] = coef2[t * 2 + k];
  }
}

// ---------------- grouped GEMM: R7 structure (best measured arm, verbatim) ----------------
// 128^2 tile, BK=64, 256 threads, global_load_lds width16, LDS [128][64] linear,
// both-sides XOR swizzle (phys chunk16 = logical ^ (row&7)) -> 0 bank conflicts.
// FFN1: bx-fast (W-panel reuse); FFN2: by-fast (h-panel reuse). XCD chunking (m204).
// R7-R14 established this is shape-bound at ~355 us/GEMM (~400 TF): scheduling,
// locality, byte-count, residency and coalescing variants all null or regress.
template<int KDIM, int NCOLS, bool FFN1>
__global__ __launch_bounds__(256) void moe_gemm_kernel(
    const bf16* __restrict__ Asrc, const bf16* __restrict__ Wsrc,
    const float* __restrict__ bias,
    const int* __restrict__ assign_tok, const float* __restrict__ slot_coef,
    const int* __restrict__ po,
    bf16* __restrict__ hout, float* __restrict__ out,
    int chunk_base, int gx)
{
  __shared__ bf16 As[BM][BK];
  __shared__ bf16 Bs[BN][BK];
  __shared__ int toks[BM];

  const int nwg = gridDim.x;
  const int lin = blockIdx.x;
  const int q = nwg >> 3, r = nwg & 7;
  const int xcd = lin & 7, idx = lin >> 3;
  const int wg = (xcd < r ? xcd * (q + 1) : r * (q + 1) + (xcd - r) * q) + idx;
  int bx, by;
  if constexpr (FFN1) { bx = wg % gx; by = wg / gx; }
  else               { by = wg % (NCOLS / BN); bx = wg / (NCOLS / BN); }

  const int po8 = po[NE];
  const int row0 = chunk_base + bx * BM;
  if (row0 >= po8) return;
  int e = 0;
  while (row0 >= po[e + 1]) ++e;
  const int bn0 = by * BN;
  const bf16* We = Wsrc + (size_t)e * ((size_t)HH * DD);
  const int tid = threadIdx.x, lane = tid & 63, wave = tid >> 6;
  if (tid < BM) toks[tid] = assign_tok[row0 + tid];
  __syncthreads();

  const int rin = lane >> 3;
  const int c8s = ((lane & 7) ^ rin) * 8;
  const bf16* asrc[4];
  const bf16* bsrc[4];
  #pragma unroll
  for (int i = 0; i < 4; ++i) {
    const int c = wave * 4 + i;
    const int row = c * 8 + rin;
    int ar;
    if constexpr (FFN1) {
      const int s = toks[row];
      ar = s < 0 ? 0 : s;
    } else {
      ar = row0 - chunk_base + row;
    }
    asrc[i] = Asrc + (size_t)ar * KDIM + c8s;
    bsrc[i] = We + (size_t)(bn0 + row) * KDIM + c8s;
  }

  const int la = lane & 15, hi = lane >> 4;
  const int wm = (wave >> 1) * 64, wn = (wave & 1) * 64;
  f32x4 acc[4][4];
  #pragma unroll
  for (int m = 0; m < 4; ++m)
    #pragma unroll
    for (int n = 0; n < 4; ++n) acc[m][n] = {0.f, 0.f, 0.f, 0.f};

  for (int k0 = 0; k0 < KDIM; k0 += BK) {
    #pragma unroll
    for (int i = 0; i < 4; ++i) gload16(asrc[i] + k0, &As[(wave * 4 + i) * 8][0]);
    #pragma unroll
    for (int i = 0; i < 4; ++i) gload16(bsrc[i] + k0, &Bs[(wave * 4 + i) * 8][0]);
    __syncthreads();
    #pragma unroll
    for (int ks = 0; ks < 2; ++ks) {
      bf16x8 af[4], bff[4];
      #pragma unroll
      for (int m = 0; m < 4; ++m) {
        const int row = wm + m * 16 + la;
        const int c8 = (ks * 4 + hi) ^ (row & 7);
        af[m] = *(const bf16x8*)(&As[row][c8 * 8]);
      }
      #pragma unroll
      for (int n = 0; n < 4; ++n) {
        const int row = wn + n * 16 + la;
        const int c8 = (ks * 4 + hi) ^ (row & 7);
        bff[n] = *(const bf16x8*)(&Bs[row][c8 * 8]);
      }
      #pragma unroll
      for (int m = 0; m < 4; ++m)
        #pragma unroll
        for (int n = 0; n < 4; ++n)
          acc[m][n] = __builtin_amdgcn_mfma_f32_16x16x32_bf16(af[m], bff[n], acc[m][n], 0, 0, 0);
    }
    __syncthreads();
  }

  if constexpr (FFN1) {
    const int hrow0 = row0 - chunk_base;
    #pragma unroll
    for (int n = 0; n < 4; ++n) {
      const int col = bn0 + wn + n * 16 + la;
      const float bb = bias[e * NCOLS + col];
      #pragma unroll
      for (int m = 0; m < 4; ++m) {
        const int rbase = wm + m * 16 + hi * 4;
        #pragma unroll
        for (int rr = 0; rr < 4; ++rr) {
          float v = acc[m][n][rr] + bb;
          v = v > 0.f ? v : 0.f;
          hout[(size_t)(hrow0 + rbase + rr) * HH + col] = (bf16)v;
        }
      }
    }
  } else {
    #pragma unroll
    for (int n = 0; n < 4; ++n) {
      const int col = bn0 + wn + n * 16 + la;
      const float bb = bias[e * NCOLS + col];
      #pragma unroll
      for (int m = 0; m < 4; ++m) {
        const int rbase = wm + m * 16 + hi * 4;
        #pragma unroll
        for (int rr = 0; rr < 4; ++rr) {
          const int trow = rbase + rr;
          const int tok = toks[trow];
          if (tok >= 0) {
            const float c = slot_coef[row0 + trow];
            atomicAdd(out + (size_t)tok * DD + col, c * (acc[m][n][rr] + bb));
          }
        }
      }
    }
  }
}

extern "C" void kernel_launch(void* const* d_in, const int* in_sizes, int n_in,
                              void* d_out, int out_size, void* d_ws, size_t ws_size,
                              hipStream_t stream) {
  const float* x      = (const float*)d_in[0];
  const float* noise  = (const float*)d_in[1];
  const float* gate_w = (const float*)d_in[2];
  const float* gate_b = (const float*)d_in[3];
  const float* var_w  = (const float*)d_in[4];
  const float* var_b  = (const float*)d_in[5];
  const float* w1     = (const float*)d_in[6];
  const float* b1     = (const float*)d_in[7];
  const float* w2     = (const float*)d_in[8];
  const float* b2     = (const float*)d_in[9];
  float* out = (float*)d_out;
  (void)in_sizes; (void)n_in; (void)out_size;

  char* ws = (char*)d_ws;
  size_t off = 0;
  auto alloc = [&](size_t bytes) {
    off = (off + 255) & ~(size_t)255;
    size_t o = off;
    off += bytes;
    return o;
  };
  bf16*  xb         = (bf16*)(ws + alloc((size_t)NTOK * DD * 2));
  float* coef2      = (float*)(ws + alloc((size_t)NTOK * 2 * 4));
  int*   t2e        = (int*)(ws + alloc((size_t)NTOK * 2 * 4));
  int*   counts     = (int*)(ws + alloc(64));   // counts[8] + cnt2[8]
  int*   cnt2       = counts + 8;
  int*   po         = (int*)(ws + alloc(64));
  int*   assign_tok = (int*)(ws + alloc((size_t)SLOT_CAP * 4));
  float* slot_coef  = (float*)(ws + alloc((size_t)SLOT_CAP * 4));
  bf16*  w1b        = (bf16*)(ws + alloc((size_t)NE * HH * DD * 2));  // 64 MB
  bf16*  w2b        = (bf16*)(ws + alloc((size_t)NE * DD * HH * 2));  // 64 MB
  off = (off + 255) & ~(size_t)255;
  const size_t h_avail = ws_size > off ? ws_size - off : 0;
  int chunk_rows = (int)(h_avail / ((size_t)HH * 2));
  chunk_rows = (chunk_rows / BM) * BM;
  if (chunk_rows < BM) chunk_rows = BM;
  if (chunk_rows > SLOT_CAP) chunk_rows = SLOT_CAP;
  bf16* hbuf = (bf16*)(ws + off);

  hipMemsetAsync(counts, 0, 64, stream);
  hipMemsetAsync(assign_tok, 0xFF, (size_t)SLOT_CAP * 4, stream);  // -1
  hipMemsetAsync(out, 0, (size_t)NTOK * DD * 4, stream);

  moe_gate_cvt_kernel<<<GATE_BLOCKS + CVT_BLOCKS, 256, 0, stream>>>(
      x, noise, gate_w, gate_b, var_w, var_b, coef2, t2e, counts, xb,
      w1, w1b, NE * HH * DD / 4, w2, w2b, NE * DD * HH / 4);
  moe_offsets_kernel<<<1, 64, 0, stream>>>(counts, po);
  moe_scatter_kernel<<<NTOK / 256, 256, 0, stream>>>(t2e, coef2, po, cnt2,
                                                     assign_tok, slot_coef);

  const int rounds = (SLOT_CAP + chunk_rows - 1) / chunk_rows;
  for (int r = 0; r < rounds; ++r) {
    const int cb = r * chunk_rows;
    const int rows_here = (cb + chunk_rows <= SLOT_CAP) ? chunk_rows : (SLOT_CAP - cb);
    const int gx = rows_here / BM;
    moe_gemm_kernel<DD, HH, true><<<gx * (HH / BN), 256, 0, stream>>>(
        xb, w1b, b1, assign_tok, slot_coef, po, hbuf, nullptr, cb, gx);
    moe_gemm_kernel<HH, DD, false><<<gx * (DD / BN), 256, 0, stream>>>(
        hbuf, w2b, b2, assign_tok, slot_coef, po, nullptr, out, cb, gx);
  }
}

// Round 16
// 917.619 us; speedup vs baseline: 1.0887x; 1.0887x over previous
//
#include <hip/hip_runtime.h>
#include <hip/hip_bf16.h>
#include <math.h>

#define NTOK 8192     // B*T
#define DD   1024
#define HH   4096
#define NE   8
#define BM 128
#define BN 128
#define BK 64
#define SLOT_CAP (2 * NTOK + NE * BM)   // 17408

typedef __bf16 bf16;
typedef __bf16 bf16x8 __attribute__((ext_vector_type(8)));
typedef __bf16 bf16x4 __attribute__((ext_vector_type(4)));
typedef float  f32x4  __attribute__((ext_vector_type(4)));

typedef __attribute__((address_space(3))) unsigned char lds_u8;
typedef const __attribute__((address_space(1))) unsigned char g_u8;

__device__ __forceinline__ void gload16(const bf16* g, bf16* l) {
  __builtin_amdgcn_global_load_lds((g_u8*)g, (lds_u8*)l, 16, 0, 0);
}

__device__ __forceinline__ float softplus_f(float v) {
  return fmaxf(v, 0.f) + log1pf(expf(-fabsf(v)));
}

// ---------------- K1: gating — 1 token per 64-thread block (max parallelism) ----------------
// R15 lesson: serial-16-token gate left 2 waves/CU (latency-bound, ~85 us).
// 8192 blocks give full TLP; gate_w/var_w (64 KB) are L2-resident on every XCD
// so the re-fetch is L2-rate (~15 us aggregate), not HBM. x->bf16 fused.
__global__ __launch_bounds__(64) void moe_gate_kernel(
    const float* __restrict__ x, const float* __restrict__ noise,
    const float* __restrict__ gate_w, const float* __restrict__ gate_b,
    const float* __restrict__ var_w,  const float* __restrict__ var_b,
    float* __restrict__ coef2, int* __restrict__ t2e, int* __restrict__ counts,
    bf16* __restrict__ xb)
{
  const int t = blockIdx.x;
  const int lane = threadIdx.x;
  const float4* x4 = (const float4*)(x + (size_t)t * DD);
  bf16x4* xb4 = (bf16x4*)(xb + (size_t)t * DD);
  const float4* gw4 = (const float4*)gate_w;
  const float4* vw4 = (const float4*)var_w;
  float pg[NE], pv[NE];
  #pragma unroll
  for (int e = 0; e < NE; ++e) { pg[e] = 0.f; pv[e] = 0.f; }
  #pragma unroll
  for (int i = 0; i < DD / 256; ++i) {
    const int d4 = i * 64 + lane;
    const float4 f = x4[d4];
    bf16x4 v;
    v[0] = (bf16)f.x; v[1] = (bf16)f.y; v[2] = (bf16)f.z; v[3] = (bf16)f.w;
    xb4[d4] = v;
    #pragma unroll
    for (int e = 0; e < NE; ++e) {
      const float4 g = gw4[e * 256 + d4];
      pg[e] = fmaf(f.x, g.x, fmaf(f.y, g.y, fmaf(f.z, g.z, fmaf(f.w, g.w, pg[e]))));
      const float4 w = vw4[e * 256 + d4];
      pv[e] = fmaf(f.x, w.x, fmaf(f.y, w.y, fmaf(f.z, w.z, fmaf(f.w, w.w, pv[e]))));
    }
  }
  #pragma unroll
  for (int e = 0; e < NE; ++e) {
    #pragma unroll
    for (int off = 32; off; off >>= 1) {
      pg[e] += __shfl_xor(pg[e], off);
      pv[e] += __shfl_xor(pv[e], off);
    }
  }
  if (lane == 0) {
    float noisy[NE];
    #pragma unroll
    for (int e = 0; e < NE; ++e) {
      const float lg = pg[e] + gate_b[e];
      const float sd = softplus_f(pv[e] + var_b[e]);
      noisy[e] = lg + noise[t * NE + e] * sd;
    }
    int i1 = 0; float n1 = noisy[0];
    #pragma unroll
    for (int e = 1; e < NE; ++e) if (noisy[e] > n1) { n1 = noisy[e]; i1 = e; }
    int i2 = -1; float n2 = -3.0e38f;
    #pragma unroll
    for (int e = 0; e < NE; ++e) if (e != i1 && noisy[e] > n2) { n2 = noisy[e]; i2 = e; }
    const float e2 = expf(n2 - n1);
    const float den = 1.f + e2;
    coef2[t * 2 + 0] = 1.f / den;
    coef2[t * 2 + 1] = e2 / den;
    t2e[t * 2 + 0] = i1;
    t2e[t * 2 + 1] = i2;
    atomicAdd(&counts[i1], 1);
    atomicAdd(&counts[i2], 1);
  }
}

// ---------------- K2: padded segment offsets (pad to BM=128) ----------------
__global__ void moe_offsets_kernel(const int* __restrict__ counts, int* __restrict__ po) {
  if (threadIdx.x == 0) {
    int acc = 0;
    po[0] = 0;
    for (int e = 0; e < NE; ++e) {
      acc += ((counts[e] + BM - 1) / BM) * BM;
      po[e + 1] = acc;
    }
  }
}

// ---------------- K3: scatter tokens into padded slots ----------------
__global__ __launch_bounds__(256) void moe_scatter_kernel(
    const int* __restrict__ t2e, const float* __restrict__ coef2,
    const int* __restrict__ po, int* __restrict__ cnt2,
    int* __restrict__ assign_tok, float* __restrict__ slot_coef)
{
  const int t = blockIdx.x * 256 + threadIdx.x;
  if (t >= NTOK) return;
  #pragma unroll
  for (int k = 0; k < 2; ++k) {
    const int e = t2e[t * 2 + k];
    const int pos = atomicAdd(&cnt2[e], 1);
    const int slot = po[e] + pos;
    assign_tok[slot] = t;
    slot_coef[slot] = coef2[t * 2 + k];
  }
}

// ---------------- K4: dual f32 -> bf16 converter ----------------
__global__ __launch_bounds__(256) void cvt2_bf16_kernel(
    const float* __restrict__ s1, bf16* __restrict__ d1, int n41,
    const float* __restrict__ s2, bf16* __restrict__ d2, int n42)
{
  for (int i = blockIdx.x * 256 + threadIdx.x; i < n41 + n42; i += gridDim.x * 256) {
    const float* s = (i < n41) ? s1 : s2;
    bf16* d = (i < n41) ? d1 : d2;
    const int j = (i < n41) ? i : i - n41;
    const float4 f = ((const float4*)s)[j];
    bf16x4 v;
    v[0] = (bf16)f.x; v[1] = (bf16)f.y; v[2] = (bf16)f.z; v[3] = (bf16)f.w;
    ((bf16x4*)d)[j] = v;
  }
}

// ---------------- grouped GEMM: R7 structure (best measured arm, verbatim) ----------------
// 128^2 tile, BK=64, 256 threads, global_load_lds width16, LDS [128][64] linear,
// both-sides XOR swizzle (phys chunk16 = logical ^ (row&7)) -> 0 bank conflicts.
// FFN1: bx-fast (W-panel reuse); FFN2: by-fast (h-panel reuse). XCD chunking (m204).
// R7-R14: scheduling, locality, byte-count, residency and coalescing variants
// all null or regress -> shape-bound at ~355 us/GEMM (~400 TF; above the m102
// reference curve for comparable K).
template<int KDIM, int NCOLS, bool FFN1>
__global__ __launch_bounds__(256) void moe_gemm_kernel(
    const bf16* __restrict__ Asrc, const bf16* __restrict__ Wsrc,
    const float* __restrict__ bias,
    const int* __restrict__ assign_tok, const float* __restrict__ slot_coef,
    const int* __restrict__ po,
    bf16* __restrict__ hout, float* __restrict__ out,
    int chunk_base, int gx)
{
  __shared__ bf16 As[BM][BK];
  __shared__ bf16 Bs[BN][BK];
  __shared__ int toks[BM];

  const int nwg = gridDim.x;
  const int lin = blockIdx.x;
  const int q = nwg >> 3, r = nwg & 7;
  const int xcd = lin & 7, idx = lin >> 3;
  const int wg = (xcd < r ? xcd * (q + 1) : r * (q + 1) + (xcd - r) * q) + idx;
  int bx, by;
  if constexpr (FFN1) { bx = wg % gx; by = wg / gx; }
  else               { by = wg % (NCOLS / BN); bx = wg / (NCOLS / BN); }

  const int po8 = po[NE];
  const int row0 = chunk_base + bx * BM;
  if (row0 >= po8) return;
  int e = 0;
  while (row0 >= po[e + 1]) ++e;
  const int bn0 = by * BN;
  const bf16* We = Wsrc + (size_t)e * ((size_t)HH * DD);
  const int tid = threadIdx.x, lane = tid & 63, wave = tid >> 6;
  if (tid < BM) toks[tid] = assign_tok[row0 + tid];
  __syncthreads();

  const int rin = lane >> 3;
  const int c8s = ((lane & 7) ^ rin) * 8;
  const bf16* asrc[4];
  const bf16* bsrc[4];
  #pragma unroll
  for (int i = 0; i < 4; ++i) {
    const int c = wave * 4 + i;
    const int row = c * 8 + rin;
    int ar;
    if constexpr (FFN1) {
      const int s = toks[row];
      ar = s < 0 ? 0 : s;
    } else {
      ar = row0 - chunk_base + row;
    }
    asrc[i] = Asrc + (size_t)ar * KDIM + c8s;
    bsrc[i] = We + (size_t)(bn0 + row) * KDIM + c8s;
  }

  const int la = lane & 15, hi = lane >> 4;
  const int wm = (wave >> 1) * 64, wn = (wave & 1) * 64;
  f32x4 acc[4][4];
  #pragma unroll
  for (int m = 0; m < 4; ++m)
    #pragma unroll
    for (int n = 0; n < 4; ++n) acc[m][n] = {0.f, 0.f, 0.f, 0.f};

  for (int k0 = 0; k0 < KDIM; k0 += BK) {
    #pragma unroll
    for (int i = 0; i < 4; ++i) gload16(asrc[i] + k0, &As[(wave * 4 + i) * 8][0]);
    #pragma unroll
    for (int i = 0; i < 4; ++i) gload16(bsrc[i] + k0, &Bs[(wave * 4 + i) * 8][0]);
    __syncthreads();
    #pragma unroll
    for (int ks = 0; ks < 2; ++ks) {
      bf16x8 af[4], bff[4];
      #pragma unroll
      for (int m = 0; m < 4; ++m) {
        const int row = wm + m * 16 + la;
        const int c8 = (ks * 4 + hi) ^ (row & 7);
        af[m] = *(const bf16x8*)(&As[row][c8 * 8]);
      }
      #pragma unroll
      for (int n = 0; n < 4; ++n) {
        const int row = wn + n * 16 + la;
        const int c8 = (ks * 4 + hi) ^ (row & 7);
        bff[n] = *(const bf16x8*)(&Bs[row][c8 * 8]);
      }
      #pragma unroll
      for (int m = 0; m < 4; ++m)
        #pragma unroll
        for (int n = 0; n < 4; ++n)
          acc[m][n] = __builtin_amdgcn_mfma_f32_16x16x32_bf16(af[m], bff[n], acc[m][n], 0, 0, 0);
    }
    __syncthreads();
  }

  if constexpr (FFN1) {
    const int hrow0 = row0 - chunk_base;
    #pragma unroll
    for (int n = 0; n < 4; ++n) {
      const int col = bn0 + wn + n * 16 + la;
      const float bb = bias[e * NCOLS + col];
      #pragma unroll
      for (int m = 0; m < 4; ++m) {
        const int rbase = wm + m * 16 + hi * 4;
        #pragma unroll
        for (int rr = 0; rr < 4; ++rr) {
          float v = acc[m][n][rr] + bb;
          v = v > 0.f ? v : 0.f;
          hout[(size_t)(hrow0 + rbase + rr) * HH + col] = (bf16)v;
        }
      }
    }
  } else {
    #pragma unroll
    for (int n = 0; n < 4; ++n) {
      const int col = bn0 + wn + n * 16 + la;
      const float bb = bias[e * NCOLS + col];
      #pragma unroll
      for (int m = 0; m < 4; ++m) {
        const int rbase = wm + m * 16 + hi * 4;
        #pragma unroll
        for (int rr = 0; rr < 4; ++rr) {
          const int trow = rbase + rr;
          const int tok = toks[trow];
          if (tok >= 0) {
            const float c = slot_coef[row0 + trow];
            atomicAdd(out + (size_t)tok * DD + col, c * (acc[m][n][rr] + bb));
          }
        }
      }
    }
  }
}

extern "C" void kernel_launch(void* const* d_in, const int* in_sizes, int n_in,
                              void* d_out, int out_size, void* d_ws, size_t ws_size,
                              hipStream_t stream) {
  const float* x      = (const float*)d_in[0];
  const float* noise  = (const float*)d_in[1];
  const float* gate_w = (const float*)d_in[2];
  const float* gate_b = (const float*)d_in[3];
  const float* var_w  = (const float*)d_in[4];
  const float* var_b  = (const float*)d_in[5];
  const float* w1     = (const float*)d_in[6];
  const float* b1     = (const float*)d_in[7];
  const float* w2     = (const float*)d_in[8];
  const float* b2     = (const float*)d_in[9];
  float* out = (float*)d_out;
  (void)in_sizes; (void)n_in; (void)out_size;

  char* ws = (char*)d_ws;
  size_t off = 0;
  auto alloc = [&](size_t bytes) {
    off = (off + 255) & ~(size_t)255;
    size_t o = off;
    off += bytes;
    return o;
  };
  bf16*  xb         = (bf16*)(ws + alloc((size_t)NTOK * DD * 2));
  float* coef2      = (float*)(ws + alloc((size_t)NTOK * 2 * 4));
  int*   t2e        = (int*)(ws + alloc((size_t)NTOK * 2 * 4));
  int*   counts     = (int*)(ws + alloc(64));   // counts[8] + cnt2[8]
  int*   cnt2       = counts + 8;
  int*   po         = (int*)(ws + alloc(64));
  int*   assign_tok = (int*)(ws + alloc((size_t)SLOT_CAP * 4));
  float* slot_coef  = (float*)(ws + alloc((size_t)SLOT_CAP * 4));
  bf16*  w1b        = (bf16*)(ws + alloc((size_t)NE * HH * DD * 2));  // 64 MB
  bf16*  w2b        = (bf16*)(ws + alloc((size_t)NE * DD * HH * 2));  // 64 MB
  off = (off + 255) & ~(size_t)255;
  const size_t h_avail = ws_size > off ? ws_size - off : 0;
  int chunk_rows = (int)(h_avail / ((size_t)HH * 2));
  chunk_rows = (chunk_rows / BM) * BM;
  if (chunk_rows < BM) chunk_rows = BM;
  if (chunk_rows > SLOT_CAP) chunk_rows = SLOT_CAP;
  bf16* hbuf = (bf16*)(ws + off);

  hipMemsetAsync(counts, 0, 64, stream);
  hipMemsetAsync(assign_tok, 0xFF, (size_t)SLOT_CAP * 4, stream);  // -1
  hipMemsetAsync(out, 0, (size_t)NTOK * DD * 4, stream);

  moe_gate_kernel<<<NTOK, 64, 0, stream>>>(x, noise, gate_w, gate_b, var_w, var_b,
                                           coef2, t2e, counts, xb);
  moe_offsets_kernel<<<1, 64, 0, stream>>>(counts, po);
  moe_scatter_kernel<<<NTOK / 256, 256, 0, stream>>>(t2e, coef2, po, cnt2,
                                                     assign_tok, slot_coef);
  cvt2_bf16_kernel<<<2048, 256, 0, stream>>>(w1, w1b, NE * HH * DD / 4,
                                             w2, w2b, NE * DD * HH / 4);

  const int rounds = (SLOT_CAP + chunk_rows - 1) / chunk_rows;
  for (int r = 0; r < rounds; ++r) {
    const int cb = r * chunk_rows;
    const int rows_here = (cb + chunk_rows <= SLOT_CAP) ? chunk_rows : (SLOT_CAP - cb);
    const int gx = rows_here / BM;
    moe_gemm_kernel<DD, HH, true><<<gx * (HH / BN), 256, 0, stream>>>(
        xb, w1b, b1, assign_tok, slot_coef, po, hbuf, nullptr, cb, gx);
    moe_gemm_kernel<HH, DD, false><<<gx * (DD / BN), 256, 0, stream>>>(
        hbuf, w2b, b2, assign_tok, slot_coef, po, nullptr, out, cb, gx);
  }
}